// Round 2
// baseline (420.295 us; speedup 1.0000x reference)
//
#include <hip/hip_runtime.h>
#include <cstdint>
#include <cstddef>

#define N_NODES 100000
#define N_EDGES 1600000
#define DIM 100
#define DPAD 128
#define ROWS_ALLOC 100096   // 1564 blocks * 64 rows

#define KBUCK 500           // buckets
#define NPB   200           // nodes per bucket (500*200 = 100000 exact)
#define BCAP  4096          // region capacity (mean 3200, sigma ~57)
#define EPB   6400          // edges per B1 block (grid 250, exact)

typedef __attribute__((ext_vector_type(8))) short s16x8;
typedef __attribute__((ext_vector_type(8))) unsigned short us8;
typedef __attribute__((ext_vector_type(4))) unsigned short us4;
typedef __attribute__((ext_vector_type(4))) float f32x4;

static __device__ __forceinline__ float bf2f(unsigned short h) {
    return __uint_as_float(((unsigned)h) << 16);
}
static __device__ __forceinline__ unsigned short f2bf(float f) {
    unsigned u = __float_as_uint(f);
    return (unsigned short)((u + 0x7FFFu + ((u >> 16) & 1u)) >> 16);   // RNE
}

// ---------------- CSR build, two-level LDS-binned counting sort ----------------
__global__ __launch_bounds__(256) void bucket_kernel(const int* __restrict__ ei,
                                                     unsigned* __restrict__ bucket_cur,
                                                     unsigned* __restrict__ regions) {
    __shared__ unsigned hist[KBUCK];
    __shared__ unsigned posl[KBUCK];
    int tid = threadIdx.x;
    int e0 = blockIdx.x * EPB;
    for (int i = tid; i < KBUCK; i += 256) hist[i] = 0;
    __syncthreads();
    for (int i = tid; i < EPB; i += 256) {
        int dst = ei[N_EDGES + e0 + i];
        int b = dst / NPB;
        atomicAdd(&hist[b], 1u);
    }
    __syncthreads();
    for (int i = tid; i < KBUCK; i += 256) {
        unsigned h = hist[i];
        posl[i] = h ? atomicAdd(&bucket_cur[i], h) : 0u;
    }
    __syncthreads();
    for (int i = tid; i < EPB; i += 256) {
        int src = ei[e0 + i];
        int dst = ei[N_EDGES + e0 + i];
        int b = dst / NPB;
        int dl = dst - b * NPB;
        unsigned r = atomicAdd(&posl[b], 1u);
        if (r < BCAP) regions[(size_t)b * BCAP + r] = ((unsigned)src << 8) | (unsigned)dl;
    }
}

__global__ __launch_bounds__(256) void csr_kernel(const unsigned* __restrict__ regions,
                                                  const unsigned* __restrict__ bucket_cur,
                                                  unsigned* __restrict__ gbase,
                                                  int* __restrict__ row_off,
                                                  int* __restrict__ cnt,
                                                  int* __restrict__ csr_src) {
    __shared__ unsigned hist[256];
    __shared__ unsigned sa[256], sb[256];
    __shared__ unsigned posl[256];
    __shared__ unsigned sh_gb;
    int tid = threadIdx.x;
    int b = blockIdx.x;
    unsigned total = bucket_cur[b];
    if (total > BCAP) total = BCAP;
    hist[tid] = 0;
    __syncthreads();
    const unsigned* reg = regions + (size_t)b * BCAP;
    for (unsigned e = tid; e < total; e += 256)
        atomicAdd(&hist[reg[e] & 0xFFu], 1u);
    __syncthreads();
    unsigned* cur = sa; unsigned* nxt = sb;
    cur[tid] = hist[tid];
    __syncthreads();
    for (int off = 1; off < 256; off <<= 1) {
        unsigned t = cur[tid];
        if (tid >= off) t += cur[tid - off];
        nxt[tid] = t;
        __syncthreads();
        unsigned* tmp = cur; cur = nxt; nxt = tmp;
    }
    unsigned excl = cur[tid] - hist[tid];
    if (tid == 0) sh_gb = atomicAdd(gbase, total);
    __syncthreads();
    unsigned gb = sh_gb;
    posl[tid] = gb + excl;
    if (tid < NPB) {
        int node = b * NPB + tid;
        cnt[node] = (int)hist[tid];
        row_off[node] = (int)(gb + excl);
    }
    __syncthreads();
    for (unsigned e = tid; e < total; e += 256) {
        unsigned p = reg[e];
        unsigned r = atomicAdd(&posl[p & 0xFFu], 1u);
        csr_src[r] = (int)(p >> 8);
    }
}

// ---------------- x (fp32, [N,100]) -> bf16 padded [N,128] ----------------
__global__ __launch_bounds__(256) void convert_pad(const float* __restrict__ X,
                                                   unsigned short* __restrict__ Xp) {
    int t = blockIdx.x * 256 + threadIdx.x;
    if (t >= N_NODES * 16) return;
    int node = t >> 4, chunk = t & 15;
    us8 o;
    if (chunk < 12) {
        const float4* p = (const float4*)(X + (size_t)node * DIM + chunk * 8);
        float4 a = p[0], b = p[1];
        o[0] = f2bf(a.x); o[1] = f2bf(a.y); o[2] = f2bf(a.z); o[3] = f2bf(a.w);
        o[4] = f2bf(b.x); o[5] = f2bf(b.y); o[6] = f2bf(b.z); o[7] = f2bf(b.w);
    } else if (chunk == 12) {
        const float4* p = (const float4*)(X + (size_t)node * DIM + 96);
        float4 a = p[0];
        o[0] = f2bf(a.x); o[1] = f2bf(a.y); o[2] = f2bf(a.z); o[3] = f2bf(a.w);
        o[4] = 0; o[5] = 0; o[6] = 0; o[7] = 0;
    } else {
        for (int i = 0; i < 8; ++i) o[i] = 0;
    }
    *(us8*)(Xp + (size_t)node * DPAD + chunk * 8) = o;
}

// ---------------- W [100k x 100n] fp32 -> Wt [128n x 128k] bf16 (transposed+padded) ----------------
__global__ __launch_bounds__(256) void build_w(const float* __restrict__ W0, const float* __restrict__ W1,
                                               const float* __restrict__ W2, const float* __restrict__ W3,
                                               const float* __restrict__ W4, const float* __restrict__ W5,
                                               unsigned short* __restrict__ Wt) {
    int t = blockIdx.x * 256 + threadIdx.x;
    if (t >= 6 * DPAD * 16) return;
    int mat = t / (DPAD * 16);
    int rem = t % (DPAD * 16);
    int nrow = rem >> 4, chunk = rem & 15;
    const float* W = (mat == 0) ? W0 : (mat == 1) ? W1 : (mat == 2) ? W2
                   : (mat == 3) ? W3 : (mat == 4) ? W4 : W5;
    us8 o;
    #pragma unroll
    for (int j = 0; j < 8; ++j) {
        int k = chunk * 8 + j;
        float v = (k < DIM && nrow < DIM) ? W[(size_t)k * DIM + nrow] : 0.f;
        o[j] = f2bf(v);
    }
    *(us8*)(Wt + (size_t)mat * DPAD * DPAD + (size_t)nrow * DPAD + chunk * 8) = o;
}

__global__ __launch_bounds__(256) void build_bias(const float* __restrict__ b0, const float* __restrict__ b1,
                                                  const float* __restrict__ b2, float* __restrict__ bp) {
    int t = blockIdx.x * 256 + threadIdx.x;
    if (t >= 3 * DPAD) return;
    int mat = t / DPAD, i = t % DPAD;
    const float* b = (mat == 0) ? b0 : (mat == 1) ? b1 : b2;
    bp[t] = (i < DIM) ? b[i] : 0.f;
}

// ---------------- mean aggregation on padded bf16 rows ----------------
__global__ __launch_bounds__(256) void aggregate_pad(const unsigned short* __restrict__ Xh,
                                                     const int* __restrict__ csr_src,
                                                     const int* __restrict__ row_off,
                                                     const int* __restrict__ cnt,
                                                     unsigned short* __restrict__ outh, int n) {
    int node = blockIdx.x * 4 + (threadIdx.x >> 6);
    if (node >= n) return;
    int lane = threadIdx.x & 63;
    int chunk = lane & 15;
    int slot  = lane >> 4;
    int start = row_off[node];
    int deg   = cnt[node];
    float acc[8];
    #pragma unroll
    for (int i = 0; i < 8; ++i) acc[i] = 0.f;
    for (int base = 0; base < deg; base += 64) {
        int m = deg - base; if (m > 64) m = 64;
        int sv = (lane < m) ? csr_src[start + base + lane] : 0;
        #pragma unroll 4
        for (int j = 0; j < m; j += 4) {
            int s = __shfl(sv, j + slot, 64);
            if (j + slot < m) {
                us8 u = *(const us8*)(Xh + (size_t)s * DPAD + chunk * 8);
                #pragma unroll
                for (int i = 0; i < 8; ++i) acc[i] += bf2f(u[i]);
            }
        }
    }
    #pragma unroll
    for (int i = 0; i < 8; ++i) {
        acc[i] += __shfl_xor(acc[i], 16, 64);
        acc[i] += __shfl_xor(acc[i], 32, 64);
    }
    if (lane < 16) {
        float inv = 1.0f / (float)(deg > 0 ? deg : 1);
        us8 o;
        #pragma unroll
        for (int i = 0; i < 8; ++i) o[i] = f2bf(acc[i] * inv);
        *(us8*)(outh + (size_t)node * DPAD + chunk * 8) = o;
    }
}

// ---------------- layer-1 GEMM, register-pinned weights, col-strip per wave ----------------
// Wave = 32-col strip (strip = wave id). Weights for the strip pinned in VGPRs (loaded once).
// MFMA operands SWAPPED (W as A-operand, node rows as B-operand) so each lane's C/D regs are
// 4 consecutive output cols of one row -> contiguous stores. Block covers 64 rows; grid 1564.
__global__ __launch_bounds__(256) void gemm_l1_strip(const unsigned short* __restrict__ Aagg,
                                                     const unsigned short* __restrict__ Aroot,
                                                     const unsigned short* __restrict__ WtA,
                                                     const unsigned short* __restrict__ WtR,
                                                     const float* __restrict__ bpad,
                                                     unsigned short* __restrict__ outp) {
    int lane  = threadIdx.x & 63;
    int strip = threadIdx.x >> 6;          // 0..3 -> cols [strip*32, strip*32+32)
    int m16   = lane & 15;
    int quad  = lane >> 4;
    int row0  = blockIdx.x * 64;

    // pinned weight fragments [ph][nt][ks]: 16 x s16x8 = 64 VGPR
    s16x8 wf[2][2][4];
    const unsigned short* Ws[2] = {WtA, WtR};
    #pragma unroll
    for (int ph = 0; ph < 2; ++ph)
        #pragma unroll
        for (int nt = 0; nt < 2; ++nt)
            #pragma unroll
            for (int ks = 0; ks < 4; ++ks)
                wf[ph][nt][ks] = *(const s16x8*)(Ws[ph] + (size_t)(strip * 32 + nt * 16 + m16) * DPAD + ks * 32 + quad * 8);

    float4 bias4[2];
    #pragma unroll
    for (int nt = 0; nt < 2; ++nt)
        bias4[nt] = *(const float4*)(bpad + strip * 32 + nt * 16 + quad * 4);

    #pragma unroll
    for (int t = 0; t < 4; ++t) {
        int m = row0 + t * 16 + m16;       // node row this lane contributes/stores
        s16x8 afA[4], afR[4];
        #pragma unroll
        for (int ks = 0; ks < 4; ++ks) {
            afA[ks] = *(const s16x8*)(Aagg  + (size_t)m * DPAD + ks * 32 + quad * 8);
            afR[ks] = *(const s16x8*)(Aroot + (size_t)m * DPAD + ks * 32 + quad * 8);
        }
        f32x4 acc[2];
        acc[0] = (f32x4){0.f, 0.f, 0.f, 0.f};
        acc[1] = (f32x4){0.f, 0.f, 0.f, 0.f};
        #pragma unroll
        for (int ks = 0; ks < 4; ++ks) {
            acc[0] = __builtin_amdgcn_mfma_f32_16x16x32_bf16(wf[0][0][ks], afA[ks], acc[0], 0, 0, 0);
            acc[1] = __builtin_amdgcn_mfma_f32_16x16x32_bf16(wf[0][1][ks], afA[ks], acc[1], 0, 0, 0);
            acc[0] = __builtin_amdgcn_mfma_f32_16x16x32_bf16(wf[1][0][ks], afR[ks], acc[0], 0, 0, 0);
            acc[1] = __builtin_amdgcn_mfma_f32_16x16x32_bf16(wf[1][1][ks], afR[ks], acc[1], 0, 0, 0);
        }
        // lane holds rows m, cols col0..col0+3 (contiguous)
        #pragma unroll
        for (int nt = 0; nt < 2; ++nt) {
            int col0 = strip * 32 + nt * 16 + quad * 4;
            us4 o;
            #pragma unroll
            for (int r = 0; r < 4; ++r) {
                float v = acc[nt][r] + ((const float*)&bias4[nt])[r];
                v = v > 0.f ? v : 0.f;
                o[r] = f2bf(v);
            }
            *(us4*)(outp + (size_t)m * DPAD + col0) = o;
        }
    }
}

// ---------------- layer-2 fused heads GEMM, same structure; mu & var share A-fragments ----------------
__global__ __launch_bounds__(256) void gemm_l2_strip(const unsigned short* __restrict__ Aagg,
                                                     const unsigned short* __restrict__ Afeat,
                                                     const unsigned short* __restrict__ WtMA,
                                                     const unsigned short* __restrict__ WtMR,
                                                     const unsigned short* __restrict__ WtVA,
                                                     const unsigned short* __restrict__ WtVR,
                                                     const float* __restrict__ bpm,
                                                     const float* __restrict__ bpv,
                                                     float* __restrict__ outMu,
                                                     float* __restrict__ outVar) {
    int lane  = threadIdx.x & 63;
    int strip = threadIdx.x >> 6;
    int m16   = lane & 15;
    int quad  = lane >> 4;
    int row0  = blockIdx.x * 64;

    // pinned weights [hd][ph][nt][ks]: 32 x s16x8 = 128 VGPR
    s16x8 wf[2][2][2][4];
    const unsigned short* Ws[2][2] = {{WtMA, WtMR}, {WtVA, WtVR}};
    #pragma unroll
    for (int hd = 0; hd < 2; ++hd)
        #pragma unroll
        for (int ph = 0; ph < 2; ++ph)
            #pragma unroll
            for (int nt = 0; nt < 2; ++nt)
                #pragma unroll
                for (int ks = 0; ks < 4; ++ks)
                    wf[hd][ph][nt][ks] = *(const s16x8*)(Ws[hd][ph] + (size_t)(strip * 32 + nt * 16 + m16) * DPAD + ks * 32 + quad * 8);

    float4 bm4[2], bv4[2];
    #pragma unroll
    for (int nt = 0; nt < 2; ++nt) {
        bm4[nt] = *(const float4*)(bpm + strip * 32 + nt * 16 + quad * 4);
        bv4[nt] = *(const float4*)(bpv + strip * 32 + nt * 16 + quad * 4);
    }

    #pragma unroll
    for (int t = 0; t < 4; ++t) {
        int m = row0 + t * 16 + m16;
        s16x8 afA[4], afF[4];
        #pragma unroll
        for (int ks = 0; ks < 4; ++ks) {
            afA[ks] = *(const s16x8*)(Aagg  + (size_t)m * DPAD + ks * 32 + quad * 8);
            afF[ks] = *(const s16x8*)(Afeat + (size_t)m * DPAD + ks * 32 + quad * 8);
        }
        f32x4 aM[2], aV[2];
        aM[0] = (f32x4){0.f,0.f,0.f,0.f}; aM[1] = (f32x4){0.f,0.f,0.f,0.f};
        aV[0] = (f32x4){0.f,0.f,0.f,0.f}; aV[1] = (f32x4){0.f,0.f,0.f,0.f};
        #pragma unroll
        for (int ks = 0; ks < 4; ++ks) {
            aM[0] = __builtin_amdgcn_mfma_f32_16x16x32_bf16(wf[0][0][0][ks], afA[ks], aM[0], 0, 0, 0);
            aM[1] = __builtin_amdgcn_mfma_f32_16x16x32_bf16(wf[0][0][1][ks], afA[ks], aM[1], 0, 0, 0);
            aV[0] = __builtin_amdgcn_mfma_f32_16x16x32_bf16(wf[1][0][0][ks], afA[ks], aV[0], 0, 0, 0);
            aV[1] = __builtin_amdgcn_mfma_f32_16x16x32_bf16(wf[1][0][1][ks], afA[ks], aV[1], 0, 0, 0);
            aM[0] = __builtin_amdgcn_mfma_f32_16x16x32_bf16(wf[0][1][0][ks], afF[ks], aM[0], 0, 0, 0);
            aM[1] = __builtin_amdgcn_mfma_f32_16x16x32_bf16(wf[0][1][1][ks], afF[ks], aM[1], 0, 0, 0);
            aV[0] = __builtin_amdgcn_mfma_f32_16x16x32_bf16(wf[1][1][0][ks], afF[ks], aV[0], 0, 0, 0);
            aV[1] = __builtin_amdgcn_mfma_f32_16x16x32_bf16(wf[1][1][1][ks], afF[ks], aV[1], 0, 0, 0);
        }
        if (m < N_NODES) {
            #pragma unroll
            for (int nt = 0; nt < 2; ++nt) {
                int col0 = strip * 32 + nt * 16 + quad * 4;
                if (col0 <= DIM - 4) {
                    float4 vm, vv;
                    vm.x = aM[nt][0] + bm4[nt].x; vm.y = aM[nt][1] + bm4[nt].y;
                    vm.z = aM[nt][2] + bm4[nt].z; vm.w = aM[nt][3] + bm4[nt].w;
                    vv.x = aV[nt][0] + bv4[nt].x; vv.y = aV[nt][1] + bv4[nt].y;
                    vv.z = aV[nt][2] + bv4[nt].z; vv.w = aV[nt][3] + bv4[nt].w;
                    *(float4*)(outMu  + (size_t)m * DIM + col0) = vm;
                    *(float4*)(outVar + (size_t)m * DIM + col0) = vv;
                }
            }
        }
    }
}

// ---------------- launch ----------------
extern "C" void kernel_launch(void* const* d_in, const int* in_sizes, int n_in,
                              void* d_out, int out_size, void* d_ws, size_t ws_size,
                              hipStream_t stream) {
    const float* x   = (const float*)d_in[0];
    const int*   ei  = (const int*)d_in[1];
    const float* Wsa = (const float*)d_in[3];
    const float* Wsr = (const float*)d_in[4];
    const float* bs  = (const float*)d_in[5];
    const float* Wma = (const float*)d_in[6];
    const float* Wmr = (const float*)d_in[7];
    const float* bm  = (const float*)d_in[8];
    const float* Wva = (const float*)d_in[9];
    const float* Wvr = (const float*)d_in[10];
    const float* bv  = (const float*)d_in[11];

    float* out_mu  = (float*)d_out;
    float* out_var = out_mu + (size_t)N_NODES * DIM;

    char* ws = (char*)d_ws;
    int*      row_off    = (int*)(ws);                       //   400,000
    int*      cnt        = (int*)(ws + 400000);              //   400,000
    unsigned* bucket_cur = (unsigned*)(ws + 800000);         //     2,048
    unsigned* gbase      = (unsigned*)(ws + 802048);         //       128
    int*      csr_src    = (int*)(ws + 802176);              // 6,400,000 -> 7,202,176
    unsigned short* Wt   = (unsigned short*)(ws + 7202176);  //   196,608 -> 7,398,784
    float*          bp   = (float*)(ws + 7398784);           //     1,536 -> 7,400,320 (pad 7,400,448)
    unsigned short* xp   = (unsigned short*)(ws + 7400448);  // 25,624,576 -> 33,025,024
    unsigned short* aggp = (unsigned short*)(ws + 33025024); // 25,624,576 -> 58,649,600
    unsigned short* ftp  = (unsigned short*)(ws + 58649600); // 25,624,576 -> 84,274,176
    // bucket regions (500*4096*4B = 8,192,000) overlay xp's slot: dead before convert_pad runs
    unsigned* regions    = (unsigned*)(ws + 7400448);

    unsigned short* WtSA = Wt;
    unsigned short* WtSR = Wt + 1 * DPAD * DPAD;
    unsigned short* WtMA = Wt + 2 * DPAD * DPAD;
    unsigned short* WtMR = Wt + 3 * DPAD * DPAD;
    unsigned short* WtVA = Wt + 4 * DPAD * DPAD;
    unsigned short* WtVR = Wt + 5 * DPAD * DPAD;
    float* bps = bp;
    float* bpm = bp + DPAD;
    float* bpv = bp + 2 * DPAD;

    hipMemsetAsync(bucket_cur, 0, 2048, stream);
    hipMemsetAsync(gbase, 0, 128, stream);

    // CSR build (uses regions overlay; must precede convert_pad)
    bucket_kernel<<<N_EDGES / EPB, 256, 0, stream>>>(ei, bucket_cur, regions);
    csr_kernel<<<KBUCK, 256, 0, stream>>>(regions, bucket_cur, gbase, row_off, cnt, csr_src);

    // packed/padded operand prep
    convert_pad<<<(N_NODES * 16 + 255) / 256, 256, 0, stream>>>(x, xp);
    build_w<<<(6 * DPAD * 16 + 255) / 256, 256, 0, stream>>>(Wsa, Wsr, Wma, Wmr, Wva, Wvr, Wt);
    build_bias<<<2, 256, 0, stream>>>(bs, bm, bv, bp);

    // layer 1
    aggregate_pad<<<N_NODES / 4, 256, 0, stream>>>(xp, csr_src, row_off, cnt, aggp, N_NODES);
    gemm_l1_strip<<<ROWS_ALLOC / 64, 256, 0, stream>>>(aggp, xp, WtSA, WtSR, bps, ftp);

    // layer 2 (aggp reused)
    aggregate_pad<<<N_NODES / 4, 256, 0, stream>>>(ftp, csr_src, row_off, cnt, aggp, N_NODES);
    gemm_l2_strip<<<ROWS_ALLOC / 64, 256, 0, stream>>>(aggp, ftp, WtMA, WtMR, WtVA, WtVR,
                                                       bpm, bpv, out_mu, out_var);
}

// Round 3
// 410.045 us; speedup vs baseline: 1.0250x; 1.0250x over previous
//
#include <hip/hip_runtime.h>
#include <cstdint>
#include <cstddef>

#define N_NODES 100000
#define N_EDGES 1600000
#define DIM 100
#define DPAD 128
#define ROWS_ALLOC 100096   // 782 blocks * 128 rows

#define RPB 128             // rows per GEMM block (8 row-tiles of 16)
#define GEMM_GRID (ROWS_ALLOC / RPB)   // 782

#define KBUCK 500           // buckets
#define NPB   200           // nodes per bucket (500*200 = 100000 exact)
#define BCAP  4096          // region capacity (mean 3200, sigma ~57)
#define EPB   6400          // edges per B1 block (grid 250, exact)

typedef __attribute__((ext_vector_type(8))) short s16x8;
typedef __attribute__((ext_vector_type(8))) unsigned short us8;
typedef __attribute__((ext_vector_type(4))) unsigned short us4;
typedef __attribute__((ext_vector_type(4))) float f32x4;

static __device__ __forceinline__ float bf2f(unsigned short h) {
    return __uint_as_float(((unsigned)h) << 16);
}
static __device__ __forceinline__ unsigned short f2bf(float f) {
    unsigned u = __float_as_uint(f);
    return (unsigned short)((u + 0x7FFFu + ((u >> 16) & 1u)) >> 16);   // RNE
}

// ---------------- CSR build, two-level LDS-binned counting sort ----------------
__global__ __launch_bounds__(256) void bucket_kernel(const int* __restrict__ ei,
                                                     unsigned* __restrict__ bucket_cur,
                                                     unsigned* __restrict__ regions) {
    __shared__ unsigned hist[KBUCK];
    __shared__ unsigned posl[KBUCK];
    int tid = threadIdx.x;
    int e0 = blockIdx.x * EPB;
    for (int i = tid; i < KBUCK; i += 256) hist[i] = 0;
    __syncthreads();
    for (int i = tid; i < EPB; i += 256) {
        int dst = ei[N_EDGES + e0 + i];
        int b = dst / NPB;
        atomicAdd(&hist[b], 1u);
    }
    __syncthreads();
    for (int i = tid; i < KBUCK; i += 256) {
        unsigned h = hist[i];
        posl[i] = h ? atomicAdd(&bucket_cur[i], h) : 0u;
    }
    __syncthreads();
    for (int i = tid; i < EPB; i += 256) {
        int src = ei[e0 + i];
        int dst = ei[N_EDGES + e0 + i];
        int b = dst / NPB;
        int dl = dst - b * NPB;
        unsigned r = atomicAdd(&posl[b], 1u);
        if (r < BCAP) regions[(size_t)b * BCAP + r] = ((unsigned)src << 8) | (unsigned)dl;
    }
}

__global__ __launch_bounds__(256) void csr_kernel(const unsigned* __restrict__ regions,
                                                  const unsigned* __restrict__ bucket_cur,
                                                  unsigned* __restrict__ gbase,
                                                  int* __restrict__ row_off,
                                                  int* __restrict__ cnt,
                                                  int* __restrict__ csr_src) {
    __shared__ unsigned hist[256];
    __shared__ unsigned sa[256], sb[256];
    __shared__ unsigned posl[256];
    __shared__ unsigned sh_gb;
    int tid = threadIdx.x;
    int b = blockIdx.x;
    unsigned total = bucket_cur[b];
    if (total > BCAP) total = BCAP;
    hist[tid] = 0;
    __syncthreads();
    const unsigned* reg = regions + (size_t)b * BCAP;
    for (unsigned e = tid; e < total; e += 256)
        atomicAdd(&hist[reg[e] & 0xFFu], 1u);
    __syncthreads();
    unsigned* cur = sa; unsigned* nxt = sb;
    cur[tid] = hist[tid];
    __syncthreads();
    for (int off = 1; off < 256; off <<= 1) {
        unsigned t = cur[tid];
        if (tid >= off) t += cur[tid - off];
        nxt[tid] = t;
        __syncthreads();
        unsigned* tmp = cur; cur = nxt; nxt = tmp;
    }
    unsigned excl = cur[tid] - hist[tid];
    if (tid == 0) sh_gb = atomicAdd(gbase, total);
    __syncthreads();
    unsigned gb = sh_gb;
    posl[tid] = gb + excl;
    if (tid < NPB) {
        int node = b * NPB + tid;
        cnt[node] = (int)hist[tid];
        row_off[node] = (int)(gb + excl);
    }
    __syncthreads();
    for (unsigned e = tid; e < total; e += 256) {
        unsigned p = reg[e];
        unsigned r = atomicAdd(&posl[p & 0xFFu], 1u);
        csr_src[r] = (int)(p >> 8);
    }
}

// ---------------- x (fp32, [N,100]) -> bf16 padded [N,128] ----------------
__global__ __launch_bounds__(256) void convert_pad(const float* __restrict__ X,
                                                   unsigned short* __restrict__ Xp) {
    int t = blockIdx.x * 256 + threadIdx.x;
    if (t >= N_NODES * 16) return;
    int node = t >> 4, chunk = t & 15;
    us8 o;
    if (chunk < 12) {
        const float4* p = (const float4*)(X + (size_t)node * DIM + chunk * 8);
        float4 a = p[0], b = p[1];
        o[0] = f2bf(a.x); o[1] = f2bf(a.y); o[2] = f2bf(a.z); o[3] = f2bf(a.w);
        o[4] = f2bf(b.x); o[5] = f2bf(b.y); o[6] = f2bf(b.z); o[7] = f2bf(b.w);
    } else if (chunk == 12) {
        const float4* p = (const float4*)(X + (size_t)node * DIM + 96);
        float4 a = p[0];
        o[0] = f2bf(a.x); o[1] = f2bf(a.y); o[2] = f2bf(a.z); o[3] = f2bf(a.w);
        o[4] = 0; o[5] = 0; o[6] = 0; o[7] = 0;
    } else {
        for (int i = 0; i < 8; ++i) o[i] = 0;
    }
    *(us8*)(Xp + (size_t)node * DPAD + chunk * 8) = o;
}

// ---------------- W [100k x 100n] fp32 -> Wt [128n x 128k] bf16 (transposed+padded) ----------------
__global__ __launch_bounds__(256) void build_w(const float* __restrict__ W0, const float* __restrict__ W1,
                                               const float* __restrict__ W2, const float* __restrict__ W3,
                                               const float* __restrict__ W4, const float* __restrict__ W5,
                                               unsigned short* __restrict__ Wt) {
    int t = blockIdx.x * 256 + threadIdx.x;
    if (t >= 6 * DPAD * 16) return;
    int mat = t / (DPAD * 16);
    int rem = t % (DPAD * 16);
    int nrow = rem >> 4, chunk = rem & 15;
    const float* W = (mat == 0) ? W0 : (mat == 1) ? W1 : (mat == 2) ? W2
                   : (mat == 3) ? W3 : (mat == 4) ? W4 : W5;
    us8 o;
    #pragma unroll
    for (int j = 0; j < 8; ++j) {
        int k = chunk * 8 + j;
        float v = (k < DIM && nrow < DIM) ? W[(size_t)k * DIM + nrow] : 0.f;
        o[j] = f2bf(v);
    }
    *(us8*)(Wt + (size_t)mat * DPAD * DPAD + (size_t)nrow * DPAD + chunk * 8) = o;
}

__global__ __launch_bounds__(256) void build_bias(const float* __restrict__ b0, const float* __restrict__ b1,
                                                  const float* __restrict__ b2, float* __restrict__ bp) {
    int t = blockIdx.x * 256 + threadIdx.x;
    if (t >= 3 * DPAD) return;
    int mat = t / DPAD, i = t % DPAD;
    const float* b = (mat == 0) ? b0 : (mat == 1) ? b1 : b2;
    bp[t] = (i < DIM) ? b[i] : 0.f;
}

// ---------------- mean aggregation on padded bf16 rows ----------------
__global__ __launch_bounds__(256) void aggregate_pad(const unsigned short* __restrict__ Xh,
                                                     const int* __restrict__ csr_src,
                                                     const int* __restrict__ row_off,
                                                     const int* __restrict__ cnt,
                                                     unsigned short* __restrict__ outh, int n) {
    int node = blockIdx.x * 4 + (threadIdx.x >> 6);
    if (node >= n) return;
    int lane = threadIdx.x & 63;
    int chunk = lane & 15;
    int slot  = lane >> 4;
    int start = row_off[node];
    int deg   = cnt[node];
    float acc[8];
    #pragma unroll
    for (int i = 0; i < 8; ++i) acc[i] = 0.f;
    for (int base = 0; base < deg; base += 64) {
        int m = deg - base; if (m > 64) m = 64;
        int sv = (lane < m) ? csr_src[start + base + lane] : 0;
        #pragma unroll 4
        for (int j = 0; j < m; j += 4) {
            int s = __shfl(sv, j + slot, 64);
            if (j + slot < m) {
                us8 u = *(const us8*)(Xh + (size_t)s * DPAD + chunk * 8);
                #pragma unroll
                for (int i = 0; i < 8; ++i) acc[i] += bf2f(u[i]);
            }
        }
    }
    #pragma unroll
    for (int i = 0; i < 8; ++i) {
        acc[i] += __shfl_xor(acc[i], 16, 64);
        acc[i] += __shfl_xor(acc[i], 32, 64);
    }
    if (lane < 16) {
        float inv = 1.0f / (float)(deg > 0 ? deg : 1);
        us8 o;
        #pragma unroll
        for (int i = 0; i < 8; ++i) o[i] = f2bf(acc[i] * inv);
        *(us8*)(outh + (size_t)node * DPAD + chunk * 8) = o;
    }
}

// ---------------- layer-1 GEMM, register-pinned weights, col-strip per wave ----------------
// launch_bounds(256,2): min 2 waves/EU -> up to 256 VGPR/wave, so the 64-VGPR weight set
// truly stays register-resident (R2 profile showed VGPR_Count=100 < the 128 needed for l2:
// compiler was re-loading "pinned" weights every tile -> MfmaUtil 7%, latency-bound).
// RPB=128 rows/block amortizes the one-time weight load over 8 row-tiles; A-fragments are
// double-buffered so tile t+1's 8 loads fly under tile t's MFMAs.
__global__ __launch_bounds__(256, 2) void gemm_l1_strip(const unsigned short* __restrict__ Aagg,
                                                        const unsigned short* __restrict__ Aroot,
                                                        const unsigned short* __restrict__ WtA,
                                                        const unsigned short* __restrict__ WtR,
                                                        const float* __restrict__ bpad,
                                                        unsigned short* __restrict__ outp) {
    int lane  = threadIdx.x & 63;
    int strip = threadIdx.x >> 6;          // 0..3 -> cols [strip*32, strip*32+32)
    int m16   = lane & 15;
    int quad  = lane >> 4;
    int row0  = blockIdx.x * RPB;

    // pinned weight fragments [ph][nt][ks]: 16 x s16x8 = 64 VGPR
    s16x8 wf[2][2][4];
    const unsigned short* Ws[2] = {WtA, WtR};
    #pragma unroll
    for (int ph = 0; ph < 2; ++ph)
        #pragma unroll
        for (int nt = 0; nt < 2; ++nt)
            #pragma unroll
            for (int ks = 0; ks < 4; ++ks)
                wf[ph][nt][ks] = *(const s16x8*)(Ws[ph] + (size_t)(strip * 32 + nt * 16 + m16) * DPAD + ks * 32 + quad * 8);

    float4 bias4[2];
    #pragma unroll
    for (int nt = 0; nt < 2; ++nt)
        bias4[nt] = *(const float4*)(bpad + strip * 32 + nt * 16 + quad * 4);

    // A-fragment double buffer (full unroll -> static indices, no scratch)
    s16x8 bA[2][4], bR[2][4];
    #pragma unroll
    for (int ks = 0; ks < 4; ++ks) {
        bA[0][ks] = *(const s16x8*)(Aagg  + (size_t)(row0 + m16) * DPAD + ks * 32 + quad * 8);
        bR[0][ks] = *(const s16x8*)(Aroot + (size_t)(row0 + m16) * DPAD + ks * 32 + quad * 8);
    }

    #pragma unroll
    for (int t = 0; t < RPB / 16; ++t) {
        int cur = t & 1;
        if (t < RPB / 16 - 1) {
            int mn = row0 + (t + 1) * 16 + m16;
            #pragma unroll
            for (int ks = 0; ks < 4; ++ks) {
                bA[cur ^ 1][ks] = *(const s16x8*)(Aagg  + (size_t)mn * DPAD + ks * 32 + quad * 8);
                bR[cur ^ 1][ks] = *(const s16x8*)(Aroot + (size_t)mn * DPAD + ks * 32 + quad * 8);
            }
        }
        f32x4 acc[2];
        acc[0] = (f32x4){0.f, 0.f, 0.f, 0.f};
        acc[1] = (f32x4){0.f, 0.f, 0.f, 0.f};
        #pragma unroll
        for (int ks = 0; ks < 4; ++ks) {
            acc[0] = __builtin_amdgcn_mfma_f32_16x16x32_bf16(wf[0][0][ks], bA[cur][ks], acc[0], 0, 0, 0);
            acc[1] = __builtin_amdgcn_mfma_f32_16x16x32_bf16(wf[0][1][ks], bA[cur][ks], acc[1], 0, 0, 0);
            acc[0] = __builtin_amdgcn_mfma_f32_16x16x32_bf16(wf[1][0][ks], bR[cur][ks], acc[0], 0, 0, 0);
            acc[1] = __builtin_amdgcn_mfma_f32_16x16x32_bf16(wf[1][1][ks], bR[cur][ks], acc[1], 0, 0, 0);
        }
        int m = row0 + t * 16 + m16;       // node row this lane stores
        #pragma unroll
        for (int nt = 0; nt < 2; ++nt) {
            int col0 = strip * 32 + nt * 16 + quad * 4;
            us4 o;
            #pragma unroll
            for (int r = 0; r < 4; ++r) {
                float v = acc[nt][r] + ((const float*)&bias4[nt])[r];
                v = v > 0.f ? v : 0.f;
                o[r] = f2bf(v);
            }
            *(us4*)(outp + (size_t)m * DPAD + col0) = o;
        }
    }
}

// ---------------- layer-2 fused heads GEMM, same structure; mu & var share A-fragments ----------------
__global__ __launch_bounds__(256, 2) void gemm_l2_strip(const unsigned short* __restrict__ Aagg,
                                                        const unsigned short* __restrict__ Afeat,
                                                        const unsigned short* __restrict__ WtMA,
                                                        const unsigned short* __restrict__ WtMR,
                                                        const unsigned short* __restrict__ WtVA,
                                                        const unsigned short* __restrict__ WtVR,
                                                        const float* __restrict__ bpm,
                                                        const float* __restrict__ bpv,
                                                        float* __restrict__ outMu,
                                                        float* __restrict__ outVar) {
    int lane  = threadIdx.x & 63;
    int strip = threadIdx.x >> 6;
    int m16   = lane & 15;
    int quad  = lane >> 4;
    int row0  = blockIdx.x * RPB;

    // pinned weights [hd][ph][nt][ks]: 32 x s16x8 = 128 VGPR (fits in 256-VGPR budget)
    s16x8 wf[2][2][2][4];
    const unsigned short* Ws[2][2] = {{WtMA, WtMR}, {WtVA, WtVR}};
    #pragma unroll
    for (int hd = 0; hd < 2; ++hd)
        #pragma unroll
        for (int ph = 0; ph < 2; ++ph)
            #pragma unroll
            for (int nt = 0; nt < 2; ++nt)
                #pragma unroll
                for (int ks = 0; ks < 4; ++ks)
                    wf[hd][ph][nt][ks] = *(const s16x8*)(Ws[hd][ph] + (size_t)(strip * 32 + nt * 16 + m16) * DPAD + ks * 32 + quad * 8);

    float4 bm4[2], bv4[2];
    #pragma unroll
    for (int nt = 0; nt < 2; ++nt) {
        bm4[nt] = *(const float4*)(bpm + strip * 32 + nt * 16 + quad * 4);
        bv4[nt] = *(const float4*)(bpv + strip * 32 + nt * 16 + quad * 4);
    }

    s16x8 bA[2][4], bF[2][4];
    #pragma unroll
    for (int ks = 0; ks < 4; ++ks) {
        bA[0][ks] = *(const s16x8*)(Aagg  + (size_t)(row0 + m16) * DPAD + ks * 32 + quad * 8);
        bF[0][ks] = *(const s16x8*)(Afeat + (size_t)(row0 + m16) * DPAD + ks * 32 + quad * 8);
    }

    #pragma unroll
    for (int t = 0; t < RPB / 16; ++t) {
        int cur = t & 1;
        if (t < RPB / 16 - 1) {
            int mn = row0 + (t + 1) * 16 + m16;
            #pragma unroll
            for (int ks = 0; ks < 4; ++ks) {
                bA[cur ^ 1][ks] = *(const s16x8*)(Aagg  + (size_t)mn * DPAD + ks * 32 + quad * 8);
                bF[cur ^ 1][ks] = *(const s16x8*)(Afeat + (size_t)mn * DPAD + ks * 32 + quad * 8);
            }
        }
        f32x4 aM[2], aV[2];
        aM[0] = (f32x4){0.f,0.f,0.f,0.f}; aM[1] = (f32x4){0.f,0.f,0.f,0.f};
        aV[0] = (f32x4){0.f,0.f,0.f,0.f}; aV[1] = (f32x4){0.f,0.f,0.f,0.f};
        #pragma unroll
        for (int ks = 0; ks < 4; ++ks) {
            aM[0] = __builtin_amdgcn_mfma_f32_16x16x32_bf16(wf[0][0][0][ks], bA[cur][ks], aM[0], 0, 0, 0);
            aM[1] = __builtin_amdgcn_mfma_f32_16x16x32_bf16(wf[0][0][1][ks], bA[cur][ks], aM[1], 0, 0, 0);
            aV[0] = __builtin_amdgcn_mfma_f32_16x16x32_bf16(wf[1][0][0][ks], bA[cur][ks], aV[0], 0, 0, 0);
            aV[1] = __builtin_amdgcn_mfma_f32_16x16x32_bf16(wf[1][0][1][ks], bA[cur][ks], aV[1], 0, 0, 0);
            aM[0] = __builtin_amdgcn_mfma_f32_16x16x32_bf16(wf[0][1][0][ks], bF[cur][ks], aM[0], 0, 0, 0);
            aM[1] = __builtin_amdgcn_mfma_f32_16x16x32_bf16(wf[0][1][1][ks], bF[cur][ks], aM[1], 0, 0, 0);
            aV[0] = __builtin_amdgcn_mfma_f32_16x16x32_bf16(wf[1][1][0][ks], bF[cur][ks], aV[0], 0, 0, 0);
            aV[1] = __builtin_amdgcn_mfma_f32_16x16x32_bf16(wf[1][1][1][ks], bF[cur][ks], aV[1], 0, 0, 0);
        }
        int m = row0 + t * 16 + m16;
        if (m < N_NODES) {
            #pragma unroll
            for (int nt = 0; nt < 2; ++nt) {
                int col0 = strip * 32 + nt * 16 + quad * 4;
                if (col0 <= DIM - 4) {
                    float4 vm, vv;
                    vm.x = aM[nt][0] + bm4[nt].x; vm.y = aM[nt][1] + bm4[nt].y;
                    vm.z = aM[nt][2] + bm4[nt].z; vm.w = aM[nt][3] + bm4[nt].w;
                    vv.x = aV[nt][0] + bv4[nt].x; vv.y = aV[nt][1] + bv4[nt].y;
                    vv.z = aV[nt][2] + bv4[nt].z; vv.w = aV[nt][3] + bv4[nt].w;
                    *(float4*)(outMu  + (size_t)m * DIM + col0) = vm;
                    *(float4*)(outVar + (size_t)m * DIM + col0) = vv;
                }
            }
        }
    }
}

// ---------------- launch ----------------
extern "C" void kernel_launch(void* const* d_in, const int* in_sizes, int n_in,
                              void* d_out, int out_size, void* d_ws, size_t ws_size,
                              hipStream_t stream) {
    const float* x   = (const float*)d_in[0];
    const int*   ei  = (const int*)d_in[1];
    const float* Wsa = (const float*)d_in[3];
    const float* Wsr = (const float*)d_in[4];
    const float* bs  = (const float*)d_in[5];
    const float* Wma = (const float*)d_in[6];
    const float* Wmr = (const float*)d_in[7];
    const float* bm  = (const float*)d_in[8];
    const float* Wva = (const float*)d_in[9];
    const float* Wvr = (const float*)d_in[10];
    const float* bv  = (const float*)d_in[11];

    float* out_mu  = (float*)d_out;
    float* out_var = out_mu + (size_t)N_NODES * DIM;

    char* ws = (char*)d_ws;
    int*      row_off    = (int*)(ws);                       //   400,000
    int*      cnt        = (int*)(ws + 400000);              //   400,000
    unsigned* bucket_cur = (unsigned*)(ws + 800000);         //     2,048
    unsigned* gbase      = (unsigned*)(ws + 802048);         //       128
    int*      csr_src    = (int*)(ws + 802176);              // 6,400,000 -> 7,202,176
    unsigned short* Wt   = (unsigned short*)(ws + 7202176);  //   196,608 -> 7,398,784
    float*          bp   = (float*)(ws + 7398784);           //     1,536 -> 7,400,320 (pad 7,400,448)
    unsigned short* xp   = (unsigned short*)(ws + 7400448);  // 25,624,576 -> 33,025,024
    unsigned short* aggp = (unsigned short*)(ws + 33025024); // 25,624,576 -> 58,649,600
    unsigned short* ftp  = (unsigned short*)(ws + 58649600); // 25,624,576 -> 84,274,176
    // bucket regions (500*4096*4B = 8,192,000) overlay xp's slot: dead before convert_pad runs
    unsigned* regions    = (unsigned*)(ws + 7400448);

    unsigned short* WtSA = Wt;
    unsigned short* WtSR = Wt + 1 * DPAD * DPAD;
    unsigned short* WtMA = Wt + 2 * DPAD * DPAD;
    unsigned short* WtMR = Wt + 3 * DPAD * DPAD;
    unsigned short* WtVA = Wt + 4 * DPAD * DPAD;
    unsigned short* WtVR = Wt + 5 * DPAD * DPAD;
    float* bps = bp;
    float* bpm = bp + DPAD;
    float* bpv = bp + 2 * DPAD;

    hipMemsetAsync(bucket_cur, 0, 2048, stream);
    hipMemsetAsync(gbase, 0, 128, stream);

    // CSR build (uses regions overlay; must precede convert_pad)
    bucket_kernel<<<N_EDGES / EPB, 256, 0, stream>>>(ei, bucket_cur, regions);
    csr_kernel<<<KBUCK, 256, 0, stream>>>(regions, bucket_cur, gbase, row_off, cnt, csr_src);

    // packed/padded operand prep
    convert_pad<<<(N_NODES * 16 + 255) / 256, 256, 0, stream>>>(x, xp);
    build_w<<<(6 * DPAD * 16 + 255) / 256, 256, 0, stream>>>(Wsa, Wsr, Wma, Wmr, Wva, Wvr, Wt);
    build_bias<<<2, 256, 0, stream>>>(bs, bm, bv, bp);

    // layer 1
    aggregate_pad<<<N_NODES / 4, 256, 0, stream>>>(xp, csr_src, row_off, cnt, aggp, N_NODES);
    gemm_l1_strip<<<GEMM_GRID, 256, 0, stream>>>(aggp, xp, WtSA, WtSR, bps, ftp);

    // layer 2 (aggp reused)
    aggregate_pad<<<N_NODES / 4, 256, 0, stream>>>(ftp, csr_src, row_off, cnt, aggp, N_NODES);
    gemm_l2_strip<<<GEMM_GRID, 256, 0, stream>>>(aggp, ftp, WtMA, WtMR, WtVA, WtVR,
                                                 bpm, bpv, out_mu, out_var);
}

// Round 4
// 400.194 us; speedup vs baseline: 1.0502x; 1.0246x over previous
//
#include <hip/hip_runtime.h>
#include <cstdint>
#include <cstddef>

#define N_NODES 100000
#define N_EDGES 1600000
#define DIM 100
#define DPAD 128
#define ROWS_ALLOC 100096   // 782 blocks * 128 rows

#define RPB 128             // rows per GEMM block (8 row-tiles of 16)
#define GEMM_GRID (ROWS_ALLOC / RPB)   // 782

#define KBUCK 500           // buckets
#define NPB   200           // nodes per bucket (500*200 = 100000 exact)
#define BCAP  4096          // region capacity (mean 3200, sigma ~57)
#define EPB   6400          // edges per B1 block (grid 250, exact)

typedef __attribute__((ext_vector_type(8))) short s16x8;
typedef __attribute__((ext_vector_type(8))) unsigned short us8;
typedef __attribute__((ext_vector_type(4))) unsigned short us4;
typedef __attribute__((ext_vector_type(4))) float f32x4;

static __device__ __forceinline__ float bf2f(unsigned short h) {
    return __uint_as_float(((unsigned)h) << 16);
}
static __device__ __forceinline__ unsigned short f2bf(float f) {
    unsigned u = __float_as_uint(f);
    return (unsigned short)((u + 0x7FFFu + ((u >> 16) & 1u)) >> 16);   // RNE
}

// ---------------- CSR build, two-level LDS-binned counting sort ----------------
__global__ __launch_bounds__(256) void bucket_kernel(const int* __restrict__ ei,
                                                     unsigned* __restrict__ bucket_cur,
                                                     unsigned* __restrict__ regions) {
    __shared__ unsigned hist[KBUCK];
    __shared__ unsigned posl[KBUCK];
    int tid = threadIdx.x;
    int e0 = blockIdx.x * EPB;
    for (int i = tid; i < KBUCK; i += 256) hist[i] = 0;
    __syncthreads();
    for (int i = tid; i < EPB; i += 256) {
        int dst = ei[N_EDGES + e0 + i];
        int b = dst / NPB;
        atomicAdd(&hist[b], 1u);
    }
    __syncthreads();
    for (int i = tid; i < KBUCK; i += 256) {
        unsigned h = hist[i];
        posl[i] = h ? atomicAdd(&bucket_cur[i], h) : 0u;
    }
    __syncthreads();
    for (int i = tid; i < EPB; i += 256) {
        int src = ei[e0 + i];
        int dst = ei[N_EDGES + e0 + i];
        int b = dst / NPB;
        int dl = dst - b * NPB;
        unsigned r = atomicAdd(&posl[b], 1u);
        if (r < BCAP) regions[(size_t)b * BCAP + r] = ((unsigned)src << 8) | (unsigned)dl;
    }
}

__global__ __launch_bounds__(256) void csr_kernel(const unsigned* __restrict__ regions,
                                                  const unsigned* __restrict__ bucket_cur,
                                                  unsigned* __restrict__ gbase,
                                                  int* __restrict__ row_off,
                                                  int* __restrict__ cnt,
                                                  int* __restrict__ csr_src) {
    __shared__ unsigned hist[256];
    __shared__ unsigned sa[256], sb[256];
    __shared__ unsigned posl[256];
    __shared__ unsigned sh_gb;
    int tid = threadIdx.x;
    int b = blockIdx.x;
    unsigned total = bucket_cur[b];
    if (total > BCAP) total = BCAP;
    hist[tid] = 0;
    __syncthreads();
    const unsigned* reg = regions + (size_t)b * BCAP;
    for (unsigned e = tid; e < total; e += 256)
        atomicAdd(&hist[reg[e] & 0xFFu], 1u);
    __syncthreads();
    unsigned* cur = sa; unsigned* nxt = sb;
    cur[tid] = hist[tid];
    __syncthreads();
    for (int off = 1; off < 256; off <<= 1) {
        unsigned t = cur[tid];
        if (tid >= off) t += cur[tid - off];
        nxt[tid] = t;
        __syncthreads();
        unsigned* tmp = cur; cur = nxt; nxt = tmp;
    }
    unsigned excl = cur[tid] - hist[tid];
    if (tid == 0) sh_gb = atomicAdd(gbase, total);
    __syncthreads();
    unsigned gb = sh_gb;
    posl[tid] = gb + excl;
    if (tid < NPB) {
        int node = b * NPB + tid;
        cnt[node] = (int)hist[tid];
        row_off[node] = (int)(gb + excl);
    }
    __syncthreads();
    for (unsigned e = tid; e < total; e += 256) {
        unsigned p = reg[e];
        unsigned r = atomicAdd(&posl[p & 0xFFu], 1u);
        csr_src[r] = (int)(p >> 8);
    }
}

// ---------------- x (fp32, [N,100]) -> bf16 padded [N,128] ----------------
__global__ __launch_bounds__(256) void convert_pad(const float* __restrict__ X,
                                                   unsigned short* __restrict__ Xp) {
    int t = blockIdx.x * 256 + threadIdx.x;
    if (t >= N_NODES * 16) return;
    int node = t >> 4, chunk = t & 15;
    us8 o;
    if (chunk < 12) {
        const float4* p = (const float4*)(X + (size_t)node * DIM + chunk * 8);
        float4 a = p[0], b = p[1];
        o[0] = f2bf(a.x); o[1] = f2bf(a.y); o[2] = f2bf(a.z); o[3] = f2bf(a.w);
        o[4] = f2bf(b.x); o[5] = f2bf(b.y); o[6] = f2bf(b.z); o[7] = f2bf(b.w);
    } else if (chunk == 12) {
        const float4* p = (const float4*)(X + (size_t)node * DIM + 96);
        float4 a = p[0];
        o[0] = f2bf(a.x); o[1] = f2bf(a.y); o[2] = f2bf(a.z); o[3] = f2bf(a.w);
        o[4] = 0; o[5] = 0; o[6] = 0; o[7] = 0;
    } else {
        for (int i = 0; i < 8; ++i) o[i] = 0;
    }
    *(us8*)(Xp + (size_t)node * DPAD + chunk * 8) = o;
}

// ---------------- W [100k x 100n] fp32 -> Wt [128n x 128k] bf16 (transposed+padded) ----------------
__global__ __launch_bounds__(256) void build_w(const float* __restrict__ W0, const float* __restrict__ W1,
                                               const float* __restrict__ W2, const float* __restrict__ W3,
                                               const float* __restrict__ W4, const float* __restrict__ W5,
                                               unsigned short* __restrict__ Wt) {
    int t = blockIdx.x * 256 + threadIdx.x;
    if (t >= 6 * DPAD * 16) return;
    int mat = t / (DPAD * 16);
    int rem = t % (DPAD * 16);
    int nrow = rem >> 4, chunk = rem & 15;
    const float* W = (mat == 0) ? W0 : (mat == 1) ? W1 : (mat == 2) ? W2
                   : (mat == 3) ? W3 : (mat == 4) ? W4 : W5;
    us8 o;
    #pragma unroll
    for (int j = 0; j < 8; ++j) {
        int k = chunk * 8 + j;
        float v = (k < DIM && nrow < DIM) ? W[(size_t)k * DIM + nrow] : 0.f;
        o[j] = f2bf(v);
    }
    *(us8*)(Wt + (size_t)mat * DPAD * DPAD + (size_t)nrow * DPAD + chunk * 8) = o;
}

__global__ __launch_bounds__(256) void build_bias(const float* __restrict__ b0, const float* __restrict__ b1,
                                                  const float* __restrict__ b2, float* __restrict__ bp) {
    int t = blockIdx.x * 256 + threadIdx.x;
    if (t >= 3 * DPAD) return;
    int mat = t / DPAD, i = t % DPAD;
    const float* b = (mat == 0) ? b0 : (mat == 1) ? b1 : b2;
    bp[t] = (i < DIM) ? b[i] : 0.f;
}

// ---------------- mean aggregation on padded bf16 rows ----------------
// R3 profile: VALUBusy 47% + HBM 42% + Occ 72% -> chain/issue-bound, not BW-bound.
// Restructure: slot-contiguous 4-edge partition, direct broadcast csr loads (no shfl in
// the address chain), guard-free main chunks, clamped+masked tail (no divergence,
// loads always issued). 4 independent gathers in flight per lane, shorter deps.
__global__ __launch_bounds__(256) void aggregate_pad(const unsigned short* __restrict__ Xh,
                                                     const int* __restrict__ csr_src,
                                                     const int* __restrict__ row_off,
                                                     const int* __restrict__ cnt,
                                                     unsigned short* __restrict__ outh, int n) {
    int node = blockIdx.x * 4 + (threadIdx.x >> 6);
    if (node >= n) return;
    int lane  = threadIdx.x & 63;
    int chunk = lane & 15;           // which 16B of the 256B row
    int slot  = lane >> 4;           // 0..3: owns edges [slot*4, slot*4+4) of each 16-chunk
    int start = row_off[node];
    int deg   = cnt[node];

    float acc[8];
    #pragma unroll
    for (int i = 0; i < 8; ++i) acc[i] = 0.f;

    const int coff = chunk * 8;
    int base = 0;
    // full 16-edge chunks: no guards, 4 back-to-back independent gathers per lane
    for (; base + 16 <= deg; base += 16) {
        const int* ep = csr_src + start + base + slot * 4;
        int s0 = ep[0], s1 = ep[1], s2 = ep[2], s3 = ep[3];
        us8 u0 = *(const us8*)(Xh + (size_t)s0 * DPAD + coff);
        us8 u1 = *(const us8*)(Xh + (size_t)s1 * DPAD + coff);
        us8 u2 = *(const us8*)(Xh + (size_t)s2 * DPAD + coff);
        us8 u3 = *(const us8*)(Xh + (size_t)s3 * DPAD + coff);
        #pragma unroll
        for (int i = 0; i < 8; ++i) acc[i] += bf2f(u0[i]);
        #pragma unroll
        for (int i = 0; i < 8; ++i) acc[i] += bf2f(u1[i]);
        #pragma unroll
        for (int i = 0; i < 8; ++i) acc[i] += bf2f(u2[i]);
        #pragma unroll
        for (int i = 0; i < 8; ++i) acc[i] += bf2f(u3[i]);
    }
    // tail: clamped addresses + float-mask FMA; loads unconditional for ILP
    if (base < deg) {                 // deg >= 1 here
        int e0 = base + slot * 4;
        #pragma unroll
        for (int t = 0; t < 4; ++t) {
            int el = e0 + t;
            bool ok = el < deg;
            int eg = start + (ok ? el : (deg - 1));   // always a valid csr slot of this node
            int s  = csr_src[eg];
            us8 u  = *(const us8*)(Xh + (size_t)s * DPAD + coff);
            float m = ok ? 1.f : 0.f;
            #pragma unroll
            for (int i = 0; i < 8; ++i) acc[i] = fmaf(bf2f(u[i]), m, acc[i]);
        }
    }
    #pragma unroll
    for (int i = 0; i < 8; ++i) {
        acc[i] += __shfl_xor(acc[i], 16, 64);
        acc[i] += __shfl_xor(acc[i], 32, 64);
    }
    if (lane < 16) {
        float inv = 1.0f / (float)(deg > 0 ? deg : 1);
        us8 o;
        #pragma unroll
        for (int i = 0; i < 8; ++i) o[i] = f2bf(acc[i] * inv);
        *(us8*)(outh + (size_t)node * DPAD + coff) = o;
    }
}

// ---------------- layer-1 GEMM, register-pinned weights, col-strip per wave ----------------
// launch_bounds(256,2): min 2 waves/EU -> up to 256 VGPR/wave, so the 64-VGPR weight set
// truly stays register-resident (R2 profile showed VGPR_Count=100: compiler was re-loading
// "pinned" weights every tile -> MfmaUtil 7%, latency-bound).
// RPB=128 rows/block amortizes the one-time weight load over 8 row-tiles; A-fragments are
// double-buffered so tile t+1's 8 loads fly under tile t's MFMAs.
__global__ __launch_bounds__(256, 2) void gemm_l1_strip(const unsigned short* __restrict__ Aagg,
                                                        const unsigned short* __restrict__ Aroot,
                                                        const unsigned short* __restrict__ WtA,
                                                        const unsigned short* __restrict__ WtR,
                                                        const float* __restrict__ bpad,
                                                        unsigned short* __restrict__ outp) {
    int lane  = threadIdx.x & 63;
    int strip = threadIdx.x >> 6;          // 0..3 -> cols [strip*32, strip*32+32)
    int m16   = lane & 15;
    int quad  = lane >> 4;
    int row0  = blockIdx.x * RPB;

    // pinned weight fragments [ph][nt][ks]: 16 x s16x8 = 64 VGPR
    s16x8 wf[2][2][4];
    const unsigned short* Ws[2] = {WtA, WtR};
    #pragma unroll
    for (int ph = 0; ph < 2; ++ph)
        #pragma unroll
        for (int nt = 0; nt < 2; ++nt)
            #pragma unroll
            for (int ks = 0; ks < 4; ++ks)
                wf[ph][nt][ks] = *(const s16x8*)(Ws[ph] + (size_t)(strip * 32 + nt * 16 + m16) * DPAD + ks * 32 + quad * 8);

    float4 bias4[2];
    #pragma unroll
    for (int nt = 0; nt < 2; ++nt)
        bias4[nt] = *(const float4*)(bpad + strip * 32 + nt * 16 + quad * 4);

    // A-fragment double buffer (full unroll -> static indices, no scratch)
    s16x8 bA[2][4], bR[2][4];
    #pragma unroll
    for (int ks = 0; ks < 4; ++ks) {
        bA[0][ks] = *(const s16x8*)(Aagg  + (size_t)(row0 + m16) * DPAD + ks * 32 + quad * 8);
        bR[0][ks] = *(const s16x8*)(Aroot + (size_t)(row0 + m16) * DPAD + ks * 32 + quad * 8);
    }

    #pragma unroll
    for (int t = 0; t < RPB / 16; ++t) {
        int cur = t & 1;
        if (t < RPB / 16 - 1) {
            int mn = row0 + (t + 1) * 16 + m16;
            #pragma unroll
            for (int ks = 0; ks < 4; ++ks) {
                bA[cur ^ 1][ks] = *(const s16x8*)(Aagg  + (size_t)mn * DPAD + ks * 32 + quad * 8);
                bR[cur ^ 1][ks] = *(const s16x8*)(Aroot + (size_t)mn * DPAD + ks * 32 + quad * 8);
            }
        }
        f32x4 acc[2];
        acc[0] = (f32x4){0.f, 0.f, 0.f, 0.f};
        acc[1] = (f32x4){0.f, 0.f, 0.f, 0.f};
        #pragma unroll
        for (int ks = 0; ks < 4; ++ks) {
            acc[0] = __builtin_amdgcn_mfma_f32_16x16x32_bf16(wf[0][0][ks], bA[cur][ks], acc[0], 0, 0, 0);
            acc[1] = __builtin_amdgcn_mfma_f32_16x16x32_bf16(wf[0][1][ks], bA[cur][ks], acc[1], 0, 0, 0);
            acc[0] = __builtin_amdgcn_mfma_f32_16x16x32_bf16(wf[1][0][ks], bR[cur][ks], acc[0], 0, 0, 0);
            acc[1] = __builtin_amdgcn_mfma_f32_16x16x32_bf16(wf[1][1][ks], bR[cur][ks], acc[1], 0, 0, 0);
        }
        int m = row0 + t * 16 + m16;       // node row this lane stores
        #pragma unroll
        for (int nt = 0; nt < 2; ++nt) {
            int col0 = strip * 32 + nt * 16 + quad * 4;
            us4 o;
            #pragma unroll
            for (int r = 0; r < 4; ++r) {
                float v = acc[nt][r] + ((const float*)&bias4[nt])[r];
                v = v > 0.f ? v : 0.f;
                o[r] = f2bf(v);
            }
            *(us4*)(outp + (size_t)m * DPAD + col0) = o;
        }
    }
}

// ---------------- layer-2 fused heads GEMM, same structure; mu & var share A-fragments ----------------
__global__ __launch_bounds__(256, 2) void gemm_l2_strip(const unsigned short* __restrict__ Aagg,
                                                        const unsigned short* __restrict__ Afeat,
                                                        const unsigned short* __restrict__ WtMA,
                                                        const unsigned short* __restrict__ WtMR,
                                                        const unsigned short* __restrict__ WtVA,
                                                        const unsigned short* __restrict__ WtVR,
                                                        const float* __restrict__ bpm,
                                                        const float* __restrict__ bpv,
                                                        float* __restrict__ outMu,
                                                        float* __restrict__ outVar) {
    int lane  = threadIdx.x & 63;
    int strip = threadIdx.x >> 6;
    int m16   = lane & 15;
    int quad  = lane >> 4;
    int row0  = blockIdx.x * RPB;

    // pinned weights [hd][ph][nt][ks]: 32 x s16x8 = 128 VGPR (fits in 256-VGPR budget)
    s16x8 wf[2][2][2][4];
    const unsigned short* Ws[2][2] = {{WtMA, WtMR}, {WtVA, WtVR}};
    #pragma unroll
    for (int hd = 0; hd < 2; ++hd)
        #pragma unroll
        for (int ph = 0; ph < 2; ++ph)
            #pragma unroll
            for (int nt = 0; nt < 2; ++nt)
                #pragma unroll
                for (int ks = 0; ks < 4; ++ks)
                    wf[hd][ph][nt][ks] = *(const s16x8*)(Ws[hd][ph] + (size_t)(strip * 32 + nt * 16 + m16) * DPAD + ks * 32 + quad * 8);

    float4 bm4[2], bv4[2];
    #pragma unroll
    for (int nt = 0; nt < 2; ++nt) {
        bm4[nt] = *(const float4*)(bpm + strip * 32 + nt * 16 + quad * 4);
        bv4[nt] = *(const float4*)(bpv + strip * 32 + nt * 16 + quad * 4);
    }

    s16x8 bA[2][4], bF[2][4];
    #pragma unroll
    for (int ks = 0; ks < 4; ++ks) {
        bA[0][ks] = *(const s16x8*)(Aagg  + (size_t)(row0 + m16) * DPAD + ks * 32 + quad * 8);
        bF[0][ks] = *(const s16x8*)(Afeat + (size_t)(row0 + m16) * DPAD + ks * 32 + quad * 8);
    }

    #pragma unroll
    for (int t = 0; t < RPB / 16; ++t) {
        int cur = t & 1;
        if (t < RPB / 16 - 1) {
            int mn = row0 + (t + 1) * 16 + m16;
            #pragma unroll
            for (int ks = 0; ks < 4; ++ks) {
                bA[cur ^ 1][ks] = *(const s16x8*)(Aagg  + (size_t)mn * DPAD + ks * 32 + quad * 8);
                bF[cur ^ 1][ks] = *(const s16x8*)(Afeat + (size_t)mn * DPAD + ks * 32 + quad * 8);
            }
        }
        f32x4 aM[2], aV[2];
        aM[0] = (f32x4){0.f,0.f,0.f,0.f}; aM[1] = (f32x4){0.f,0.f,0.f,0.f};
        aV[0] = (f32x4){0.f,0.f,0.f,0.f}; aV[1] = (f32x4){0.f,0.f,0.f,0.f};
        #pragma unroll
        for (int ks = 0; ks < 4; ++ks) {
            aM[0] = __builtin_amdgcn_mfma_f32_16x16x32_bf16(wf[0][0][0][ks], bA[cur][ks], aM[0], 0, 0, 0);
            aM[1] = __builtin_amdgcn_mfma_f32_16x16x32_bf16(wf[0][0][1][ks], bA[cur][ks], aM[1], 0, 0, 0);
            aV[0] = __builtin_amdgcn_mfma_f32_16x16x32_bf16(wf[1][0][0][ks], bA[cur][ks], aV[0], 0, 0, 0);
            aV[1] = __builtin_amdgcn_mfma_f32_16x16x32_bf16(wf[1][0][1][ks], bA[cur][ks], aV[1], 0, 0, 0);
            aM[0] = __builtin_amdgcn_mfma_f32_16x16x32_bf16(wf[0][1][0][ks], bF[cur][ks], aM[0], 0, 0, 0);
            aM[1] = __builtin_amdgcn_mfma_f32_16x16x32_bf16(wf[0][1][1][ks], bF[cur][ks], aM[1], 0, 0, 0);
            aV[0] = __builtin_amdgcn_mfma_f32_16x16x32_bf16(wf[1][1][0][ks], bF[cur][ks], aV[0], 0, 0, 0);
            aV[1] = __builtin_amdgcn_mfma_f32_16x16x32_bf16(wf[1][1][1][ks], bF[cur][ks], aV[1], 0, 0, 0);
        }
        int m = row0 + t * 16 + m16;
        if (m < N_NODES) {
            #pragma unroll
            for (int nt = 0; nt < 2; ++nt) {
                int col0 = strip * 32 + nt * 16 + quad * 4;
                if (col0 <= DIM - 4) {
                    float4 vm, vv;
                    vm.x = aM[nt][0] + bm4[nt].x; vm.y = aM[nt][1] + bm4[nt].y;
                    vm.z = aM[nt][2] + bm4[nt].z; vm.w = aM[nt][3] + bm4[nt].w;
                    vv.x = aV[nt][0] + bv4[nt].x; vv.y = aV[nt][1] + bv4[nt].y;
                    vv.z = aV[nt][2] + bv4[nt].z; vv.w = aV[nt][3] + bv4[nt].w;
                    *(float4*)(outMu  + (size_t)m * DIM + col0) = vm;
                    *(float4*)(outVar + (size_t)m * DIM + col0) = vv;
                }
            }
        }
    }
}

// ---------------- launch ----------------
extern "C" void kernel_launch(void* const* d_in, const int* in_sizes, int n_in,
                              void* d_out, int out_size, void* d_ws, size_t ws_size,
                              hipStream_t stream) {
    const float* x   = (const float*)d_in[0];
    const int*   ei  = (const int*)d_in[1];
    const float* Wsa = (const float*)d_in[3];
    const float* Wsr = (const float*)d_in[4];
    const float* bs  = (const float*)d_in[5];
    const float* Wma = (const float*)d_in[6];
    const float* Wmr = (const float*)d_in[7];
    const float* bm  = (const float*)d_in[8];
    const float* Wva = (const float*)d_in[9];
    const float* Wvr = (const float*)d_in[10];
    const float* bv  = (const float*)d_in[11];

    float* out_mu  = (float*)d_out;
    float* out_var = out_mu + (size_t)N_NODES * DIM;

    char* ws = (char*)d_ws;
    int*      row_off    = (int*)(ws);                       //   400,000
    int*      cnt        = (int*)(ws + 400000);              //   400,000
    unsigned* bucket_cur = (unsigned*)(ws + 800000);         //     2,048
    unsigned* gbase      = (unsigned*)(ws + 802048);         //       128
    int*      csr_src    = (int*)(ws + 802176);              // 6,400,000 -> 7,202,176
    unsigned short* Wt   = (unsigned short*)(ws + 7202176);  //   196,608 -> 7,398,784
    float*          bp   = (float*)(ws + 7398784);           //     1,536 -> 7,400,320 (pad 7,400,448)
    unsigned short* xp   = (unsigned short*)(ws + 7400448);  // 25,624,576 -> 33,025,024
    unsigned short* aggp = (unsigned short*)(ws + 33025024); // 25,624,576 -> 58,649,600
    unsigned short* ftp  = (unsigned short*)(ws + 58649600); // 25,624,576 -> 84,274,176
    // bucket regions (500*4096*4B = 8,192,000) overlay xp's slot: dead before convert_pad runs
    unsigned* regions    = (unsigned*)(ws + 7400448);

    unsigned short* WtSA = Wt;
    unsigned short* WtSR = Wt + 1 * DPAD * DPAD;
    unsigned short* WtMA = Wt + 2 * DPAD * DPAD;
    unsigned short* WtMR = Wt + 3 * DPAD * DPAD;
    unsigned short* WtVA = Wt + 4 * DPAD * DPAD;
    unsigned short* WtVR = Wt + 5 * DPAD * DPAD;
    float* bps = bp;
    float* bpm = bp + DPAD;
    float* bpv = bp + 2 * DPAD;

    hipMemsetAsync(bucket_cur, 0, 2048, stream);
    hipMemsetAsync(gbase, 0, 128, stream);

    // CSR build (uses regions overlay; must precede convert_pad)
    bucket_kernel<<<N_EDGES / EPB, 256, 0, stream>>>(ei, bucket_cur, regions);
    csr_kernel<<<KBUCK, 256, 0, stream>>>(regions, bucket_cur, gbase, row_off, cnt, csr_src);

    // packed/padded operand prep
    convert_pad<<<(N_NODES * 16 + 255) / 256, 256, 0, stream>>>(x, xp);
    build_w<<<(6 * DPAD * 16 + 255) / 256, 256, 0, stream>>>(Wsa, Wsr, Wma, Wmr, Wva, Wvr, Wt);
    build_bias<<<2, 256, 0, stream>>>(bs, bm, bv, bp);

    // layer 1
    aggregate_pad<<<N_NODES / 4, 256, 0, stream>>>(xp, csr_src, row_off, cnt, aggp, N_NODES);
    gemm_l1_strip<<<GEMM_GRID, 256, 0, stream>>>(aggp, xp, WtSA, WtSR, bps, ftp);

    // layer 2 (aggp reused)
    aggregate_pad<<<N_NODES / 4, 256, 0, stream>>>(ftp, csr_src, row_off, cnt, aggp, N_NODES);
    gemm_l2_strip<<<GEMM_GRID, 256, 0, stream>>>(aggp, ftp, WtMA, WtMR, WtVA, WtVR,
                                                 bpm, bpv, out_mu, out_var);
}